// Round 8
// baseline (135.189 us; speedup 1.0000x reference)
//
#include <hip/hip_runtime.h>
#include <stdint.h>

typedef __bf16 bf16;
typedef bf16 bf16x8 __attribute__((ext_vector_type(8)));
typedef float f32x4 __attribute__((ext_vector_type(4)));
typedef float f32x16 __attribute__((ext_vector_type(16)));
typedef unsigned short u16x8 __attribute__((ext_vector_type(8)));
typedef unsigned short u16x4 __attribute__((ext_vector_type(4)));

__device__ __forceinline__ unsigned short f2bfu(float f) {
    union { bf16 h; unsigned short u; } x;
    x.h = (bf16)f;
    return x.u;
}
__device__ __forceinline__ float bfu2f(unsigned short u) {
    union { unsigned int i; float f; } x;
    x.i = ((unsigned int)u) << 16;
    return x.f;
}
__device__ __forceinline__ unsigned int pack2bf(float a, float b) {
    union { bf16 h[2]; unsigned int u; } x;
    x.h[0] = (bf16)a; x.h[1] = (bf16)b;
    return x.u;
}
// v_permlane32_swap_b32: a's upper 32 lanes <-> b's lower 32 lanes.
__device__ __forceinline__ void pl32_swap(unsigned int &a, unsigned int &b) {
    asm volatile("v_permlane32_swap_b32 %0, %1" : "+v"(a), "+v"(b));
}

// global -> LDS async copy, 16B per lane. LDS dest must be wave-uniform.
__device__ __forceinline__ void gld_lds16(const void* g, void* l) {
    __builtin_amdgcn_global_load_lds(
        (const __attribute__((address_space(1))) unsigned int*)(uintptr_t)g,
        (__attribute__((address_space(3))) unsigned int*)(unsigned int)(uintptr_t)l,
        16, 0, 0);
}

// ---------------- cast fp32 -> bf16, 8 elems/thread ----------------
__global__ void cast_bf16_kernel(const float* __restrict__ in,
                                 unsigned short* __restrict__ out, int n8) {
    int i = blockIdx.x * blockDim.x + threadIdx.x;
    if (i >= n8) return;
    const f32x4* p = (const f32x4*)(in + (size_t)i * 8);
    f32x4 a = p[0], b = p[1];
    u16x8 o;
    o[0]=f2bfu(a[0]); o[1]=f2bfu(a[1]); o[2]=f2bfu(a[2]); o[3]=f2bfu(a[3]);
    o[4]=f2bfu(b[0]); o[5]=f2bfu(b[1]); o[6]=f2bfu(b[2]); o[7]=f2bfu(b[3]);
    *(u16x8*)(out + (size_t)i * 8) = o;
}

// ---------------- RoPE in-place on q,k sections of qkv [4096][3072] bf16 ----
// q additionally scaled by 0.125*log2(e) (softmax scale folded + exp->exp2).
__global__ void rope_kernel(unsigned short* __restrict__ qkv,
                            const float* __restrict__ cosp,
                            const float* __restrict__ sinp) {
    int tid = blockIdx.x * blockDim.x + threadIdx.x;   // 524288 total
    int i8  = tid & 3;
    int h   = (tid >> 2) & 15;
    int sel = (tid >> 6) & 1;
    int n   = (tid >> 7) & 2047;
    int b   = tid >> 18;
    size_t base = ((size_t)(b*2048 + n))*3072 + sel*1024 + h*64 + i8*8;
    u16x8 x1 = *(u16x8*)(qkv + base);
    u16x8 x2 = *(u16x8*)(qkv + base + 32);
    const f32x4* cp = (const f32x4*)(cosp + n*64 + i8*8);
    const f32x4* sp = (const f32x4*)(sinp + n*64 + i8*8);
    f32x4 c0 = cp[0], c1 = cp[1], s0 = sp[0], s1 = sp[1];
    float scale = sel ? 1.0f : (0.125f * 1.44269504088896f);
    u16x8 o1, o2;
#pragma unroll
    for (int j = 0; j < 8; j++) {
        float cc = (j < 4) ? c0[j] : c1[j-4];
        float ss = (j < 4) ? s0[j] : s1[j-4];
        float a = bfu2f(x1[j]), d = bfu2f(x2[j]);
        o1[j] = f2bfu((a*cc - d*ss) * scale);
        o2[j] = f2bfu((d*cc + a*ss) * scale);
    }
    *(u16x8*)(qkv + base)      = o1;
    *(u16x8*)(qkv + base + 32) = o2;
}

// ---------------- QKV GEMM, 256x256 tile, 8 waves, triple-buffer 2-ahead ----
// C[M,N] = A[M,K] * B[N,K]^T, bf16 out. BK=32, 32 K-tiles (K=1024).
// Counted vmcnt(4) in main loop (never 0), raw s_barrier (no implicit drain),
// T2 XOR swizzle (row&3)<<4 on stage-source AND ds_read, T5 setprio.
__global__ __launch_bounds__(512, 2) void gemm_qkv8(
    const unsigned short* __restrict__ A, const unsigned short* __restrict__ B,
    unsigned short* __restrict__ C, int M, int N, int K)
{
    extern __shared__ char smem[];        // 3 bufs x (A 16KB + B 16KB) = 96KB
    int nwgx = gridDim.x;
    int nwg  = nwgx * gridDim.y;          // 192, divisible by 8
    int orig = blockIdx.y * nwgx + blockIdx.x;
    int cpx  = nwg >> 3;
    int wg   = (orig & 7) * cpx + (orig >> 3);
    int bx = wg % nwgx, by = wg / nwgx;
    int m0 = by << 8, n0 = bx << 8;
    int t  = threadIdx.x;
    int wv = t >> 6, l = t & 63;
    int fr = l & 15, fq = l >> 4;
    int wm = (wv >> 2) << 7;              // wave_m * 128
    int wn = (wv & 3) << 6;               // wave_n * 64
    int aswz = (fr & 3) << 4;

    auto stage = [&](int kt, int bsel) {
        int k0 = kt << 5;
        char* base = smem + (bsel << 15);
#pragma unroll
        for (int j = 0; j < 2; ++j) {
            int y   = (j << 13) + t * 16;             // linear LDS byte (chunk)
            int ly  = y ^ (((y >> 6) & 3) << 4);      // inverse-swizzled source
            int row = ly >> 6;
            int colu = (ly & 63) >> 1;
            gld_lds16(A + (size_t)(m0 + row) * K + k0 + colu,
                      base + ((j << 13) + (wv << 10)));
            gld_lds16(B + (size_t)(n0 + row) * K + k0 + colu,
                      base + 16384 + ((j << 13) + (wv << 10)));
        }
    };

    f32x4 acc[8][4];
#pragma unroll
    for (int m = 0; m < 8; ++m)
#pragma unroll
        for (int n = 0; n < 4; ++n) acc[m][n] = f32x4{0.f, 0.f, 0.f, 0.f};

    stage(0, 0);
    stage(1, 1);
    int cb = 0;
    for (int kt = 0; kt < 32; ++kt) {
        // wait own tile-kt loads (4 oldest); tile kt+1's 4 stay in flight
        if (kt < 31) asm volatile("s_waitcnt vmcnt(4)" ::: "memory");
        else         asm volatile("s_waitcnt vmcnt(0)" ::: "memory");
        __builtin_amdgcn_s_barrier();     // all waves: tile kt ready; tile kt-1
                                          // fully consumed -> its buffer free
        if (kt + 2 < 32) {
            int sb = cb - 1; if (sb < 0) sb = 2;      // (cb+2)%3
            stage(kt + 2, sb);
        }
        const char* base = smem + (cb << 15);
        const char* Ab = base + ((wm + fr) << 6) + ((fq * 16) ^ aswz);
        const char* Bb = base + 16384 + ((wn + fr) << 6) + ((fq * 16) ^ aswz);
        bf16x8 bfr[4], af[4];
#pragma unroll
        for (int n = 0; n < 4; ++n) bfr[n] = *(const bf16x8*)(Bb + (n << 10));
#pragma unroll
        for (int m = 0; m < 4; ++m) af[m]  = *(const bf16x8*)(Ab + (m << 10));
        __builtin_amdgcn_s_barrier();
        __builtin_amdgcn_s_setprio(1);
#pragma unroll
        for (int m = 0; m < 4; ++m)
#pragma unroll
            for (int n = 0; n < 4; ++n)
                acc[m][n] = __builtin_amdgcn_mfma_f32_16x16x32_bf16(af[m], bfr[n], acc[m][n], 0, 0, 0);
        __builtin_amdgcn_s_setprio(0);
#pragma unroll
        for (int m = 0; m < 4; ++m) af[m] = *(const bf16x8*)(Ab + ((m + 4) << 10));
        __builtin_amdgcn_s_barrier();
        __builtin_amdgcn_s_setprio(1);
#pragma unroll
        for (int m = 0; m < 4; ++m)
#pragma unroll
            for (int n = 0; n < 4; ++n)
                acc[m + 4][n] = __builtin_amdgcn_mfma_f32_16x16x32_bf16(af[m], bfr[n], acc[m + 4][n], 0, 0, 0);
        __builtin_amdgcn_s_setprio(0);
        cb = (cb == 2) ? 0 : cb + 1;
    }
    // epilogue: C[row][col], row from A-side (fq*4+e), col from B-side (fr)
#pragma unroll
    for (int m = 0; m < 8; ++m)
#pragma unroll
        for (int n = 0; n < 4; ++n)
#pragma unroll
            for (int e = 0; e < 4; ++e) {
                int row = m0 + wm + m * 16 + fq * 4 + e;
                int col = n0 + wn + n * 16 + fr;
                C[(size_t)row * N + col] = f2bfu(acc[m][n][e]);
            }
}

// ---------------- bf16 GEMM: C[M,N] = A[M,K] * B[N,K]^T (both K-contig) -----
// T3-lite: double-buffered LDS, ONE barrier per K-step, stage(t+1) issued
// AFTER the barrier so gld_lds stays in flight through compute(t).
template<int OUT_F32>
__global__ __launch_bounds__(256, 2) void gemm_bt(
    const unsigned short* __restrict__ A, const unsigned short* __restrict__ B,
    void* __restrict__ Cp, const float* __restrict__ bias,
    int M, int N, int K)
{
    __shared__ __align__(16) unsigned short As[2][128*32];
    __shared__ __align__(16) unsigned short Bs[2][128*32];
    int nwg  = gridDim.x * gridDim.y;
    int orig = blockIdx.y * gridDim.x + blockIdx.x;
    int qq = nwg >> 3, rr = nwg & 7;
    int xcd = orig & 7, idx = orig >> 3;
    int wg = (xcd < rr) ? (xcd*(qq+1) + idx) : (rr*(qq+1) + (xcd-rr)*qq + idx);
    int bx = wg % gridDim.x, by = wg / gridDim.x;
    int m0 = by * 128, n0 = bx * 128;
    int t = threadIdx.x;
    int w = t >> 6, l = t & 63;
    int c = l & 15, g = l >> 4;
    int wm = (w >> 1) * 64, wn = (w & 1) * 64;

    auto stage = [&](int kt, int bsel) {
#pragma unroll
        for (int r2 = 0; r2 < 2; ++r2) {
            int xb = w*2048 + r2*1024;        // byte base of wave chunk
            int x  = xb + l*16;               // per-lane byte
            int row  = x >> 6;                // 64B per row (32 bf16)
            int colu = (x & 63) >> 1;         // ushort col
            int k0 = kt << 5;
            gld_lds16(A + (size_t)(m0+row)*K + k0 + colu, (void*)(As[bsel] + (xb >> 1)));
            gld_lds16(B + (size_t)(n0+row)*K + k0 + colu, (void*)(Bs[bsel] + (xb >> 1)));
        }
    };

    f32x4 acc[4][4];
#pragma unroll
    for (int i = 0; i < 4; i++)
#pragma unroll
        for (int j = 0; j < 4; j++) acc[i][j] = f32x4{0.f,0.f,0.f,0.f};

    int nkt = K >> 5;
    stage(0, 0);
    int cur = 0;
    for (int kt = 0; kt < nkt; ++kt) {
        __syncthreads();                      // drains stage(kt); frees buf cur^1
        if (kt + 1 < nkt) stage(kt + 1, cur ^ 1);   // in flight through compute
        const unsigned short* Ab = As[cur] + wm*32;
        const unsigned short* Bb = Bs[cur] + wn*32;
        bf16x8 af[4], bfr[4];
#pragma unroll
        for (int i = 0; i < 4; i++) af[i]  = *(const bf16x8*)(Ab + (i*16+c)*32 + g*8);
#pragma unroll
        for (int i = 0; i < 4; i++) bfr[i] = *(const bf16x8*)(Bb + (i*16+c)*32 + g*8);
#pragma unroll
        for (int i = 0; i < 4; i++)
#pragma unroll
            for (int j = 0; j < 4; j++)
                acc[i][j] = __builtin_amdgcn_mfma_f32_16x16x32_bf16(af[i], bfr[j], acc[i][j], 0, 0, 0);
        cur ^= 1;
    }
#pragma unroll
    for (int i = 0; i < 4; i++)
#pragma unroll
        for (int j = 0; j < 4; j++)
#pragma unroll
            for (int e = 0; e < 4; e++) {
                int row = m0 + wm + i*16 + g*4 + e;
                int col = n0 + wn + j*16 + c;
                float v = acc[i][j][e];
                if (bias) v += bias[col];
                if (OUT_F32) ((float*)Cp)[(size_t)row*N + col] = v;
                else ((unsigned short*)Cp)[(size_t)row*N + col] = f2bfu(v);
            }
}

// ---------------- flash attention, 32x32 MFMA + permlane32_swap -------------
// grid (16 q-tiles, 32 bh). block 256 = 4 waves; wave owns 32 q rows.
// T3-lite pipeline: double-buffered K/V LDS, ONE barrier per kv-tile;
// stage(t+1) (gld_lds K + global V->regs) issued AFTER the barrier so the
// loads stay in flight through compute(t). V ds_write happens at top of the
// next iteration (regs had a full compute phase to arrive).
__global__ __launch_bounds__(256, 2) void attn_kernel(
    const unsigned short* __restrict__ qkv, unsigned short* __restrict__ outp)
{
    __shared__ __align__(16) unsigned short Ks[2][64*64];  // K tiles, swizzled
    __shared__ __align__(16) unsigned short Vt[2][64*64];  // V^T tiles, swizzled
    int bh = blockIdx.y;
    int b = bh >> 4, h = bh & 15;
    int q0 = blockIdx.x << 7;
    int t = threadIdx.x;
    int w = t >> 6, l = t & 63;
    int q = l & 31, hi = l >> 5;
    int qw = q0 + w*32;
    size_t bh_base = ((size_t)b*2048)*3072 + (size_t)h*64;

    auto stageK = [&](int kv0, int bsel) {
#pragma unroll
        for (int r2 = 0; r2 < 2; ++r2) {
            int xb = w*2048 + r2*1024;
            int x  = xb + l*16;
            int row  = x >> 7;                 // 128B rows
            int scolb = (x & 127) ^ ((row & 7) << 4);
            gld_lds16(qkv + bh_base + 1024 + (size_t)(kv0 + row)*3072 + (scolb >> 1),
                      (void*)(Ks[bsel] + (xb >> 1)));
        }
    };
    auto loadV = [&](int kv0, u16x8 &v0, u16x8 &v1) {
        int p  = t >> 3;
        int hb = (t & 7) << 3;
        const unsigned short* src = qkv + bh_base + 2048 + (size_t)(kv0 + 2*p)*3072 + hb;
        v0 = *(const u16x8*)src;
        v1 = *(const u16x8*)(src + 3072);
    };
    auto writeV = [&](const u16x8 &v0, const u16x8 &v1, int bsel) {
        int p  = t >> 3;
        int hb = (t & 7) << 3;
#pragma unroll
        for (int e = 0; e < 8; e++) {
            int hd = hb + e;
            int colb = (4*p) ^ ((((hd) ^ (hd >> 3)) & 7) << 4);
            *(unsigned int*)((char*)Vt[bsel] + hd*128 + colb) =
                (unsigned int)v0[e] | ((unsigned int)v1[e] << 16);
        }
    };

    // Q B-frags: qf[dc] = Q[qw+q][dc*16 + hi*8 .. +7]
    bf16x8 qf[4];
#pragma unroll
    for (int dc = 0; dc < 4; dc++)
        qf[dc] = *(const bf16x8*)(qkv + bh_base + (size_t)(qw + q)*3072 + dc*16 + hi*8);

    f32x16 oacc[2];
#pragma unroll
    for (int e = 0; e < 16; e++) { oacc[0][e] = 0.f; oacc[1][e] = 0.f; }
    float lsum = 0.f;

    u16x8 vc0, vc1, vn0, vn1;
    stageK(0, 0);
    loadV(0, vc0, vc1);
    int cur = 0;

    for (int kvt = 0; kvt < 32; ++kvt) {
        writeV(vc0, vc1, cur);                 // waits V(t) regs (counted vmcnt)
        __syncthreads();                       // drains K(t) gld_lds + V writes;
                                               // all waves done compute(t-1)
        if (kvt < 31) {
            int kv0n = (kvt + 1) << 6;
            stageK(kv0n, cur ^ 1);             // in flight through compute(t)
            loadV(kv0n, vn0, vn1);
        }
        const char* ksb = (const char*)Ks[cur];
        const char* vtb = (const char*)Vt[cur];

#pragma unroll
        for (int sblk = 0; sblk < 2; ++sblk) {
            // S^T block [32 kv][32 q] = K * Q^T : 4 MFMA over d
            f32x16 st;
#pragma unroll
            for (int e = 0; e < 16; e++) st[e] = 0.f;
            int krow = sblk*32 + q;
            int ksw = (krow & 7) << 4;
#pragma unroll
            for (int dc = 0; dc < 4; ++dc) {
                bf16x8 kf = *(const bf16x8*)(ksb + krow*128 + ((dc*32 + hi*16) ^ ksw));
                st = __builtin_amdgcn_mfma_f32_32x32x16_bf16(kf, qf[dc], st, 0, 0, 0);
            }
            // softmax: P = exp2(S') (log2e pre-folded); pack pairs; row-sum
            unsigned int wds[8];
#pragma unroll
            for (int m = 0; m < 8; m++) {
                float p0 = __builtin_amdgcn_exp2f(st[2*m]);
                float p1 = __builtin_amdgcn_exp2f(st[2*m+1]);
                lsum += p0 + p1;
                wds[m] = pack2bf(p0, p1);
            }
            // PV: for each 16-kv chunk assemble P^T B-frag via 2 swaps, 2 MFMA
#pragma unroll
            for (int half = 0; half < 2; ++half) {
                unsigned int a0 = wds[half*4 + 0], b0 = wds[half*4 + 2];
                unsigned int a1 = wds[half*4 + 1], b1 = wds[half*4 + 3];
                pl32_swap(a0, b0);
                pl32_swap(a1, b1);
                union { unsigned int u[4]; bf16x8 v; } pf;
                pf.u[0] = a0; pf.u[1] = a1; pf.u[2] = b0; pf.u[3] = b1;
                int kc = sblk*2 + half;
#pragma unroll
                for (int hdblk = 0; hdblk < 2; ++hdblk) {
                    int hd = hdblk*32 + q;
                    int vsw = ((hd ^ (hd >> 3)) & 7) << 4;
                    bf16x8 vf = *(const bf16x8*)(vtb + hd*128 + ((kc*32 + hi*16) ^ vsw));
                    oacc[hdblk] = __builtin_amdgcn_mfma_f32_32x32x16_bf16(vf, pf.v, oacc[hdblk], 0, 0, 0);
                }
            }
        }
        vc0 = vn0; vc1 = vn1;
        cur ^= 1;
    }
    // finalize: full column sum needs partner half (rows +-4), then scale+store
    float ltot = lsum + __shfl_xor(lsum, 32, 64);
    float rinv = 1.0f / ltot;
    // lane holds O^T[hd][q], hd = (reg&3) + 8*(reg>>2) + 4*hi + 32*hdblk.
    // regs within a quad are consecutive hd -> 8B packed stores.
    size_t orow = (size_t)(b*2048 + qw + q) * 1024 + h*64;
#pragma unroll
    for (int hdblk = 0; hdblk < 2; ++hdblk)
#pragma unroll
        for (int quad = 0; quad < 4; ++quad) {
            u16x4 o4;
#pragma unroll
            for (int j = 0; j < 4; j++)
                o4[j] = f2bfu(oacc[hdblk][quad*4 + j] * rinv);
            *(u16x4*)(outp + orow + hdblk*32 + quad*8 + hi*4) = o4;
        }
}

// ---------------- launch ----------------------------------------------------
extern "C" void kernel_launch(void* const* d_in, const int* in_sizes, int n_in,
                              void* d_out, int out_size, void* d_ws, size_t ws_size,
                              hipStream_t stream) {
    const float* x      = (const float*)d_in[0];
    const float* cosp   = (const float*)d_in[1];
    const float* sinp   = (const float*)d_in[2];
    const float* qkv_w  = (const float*)d_in[3];
    const float* proj_w = (const float*)d_in[4];
    const float* proj_b = (const float*)d_in[5];

    char* ws = (char*)d_ws;
    // ws layout (40 MB total):
    // [0,8MB)   xb   : x in bf16 [4096][1024]   (reused as attn output later)
    // [8,14MB)  wqkvb: qkv_w bf16 [3072][1024]
    // [14,16MB) wprojb: proj_w bf16 [1024][1024]
    // [16,40MB) qkvb : qkv bf16 [4096][3072]
    unsigned short* xb     = (unsigned short*)(ws);
    unsigned short* wqkvb  = (unsigned short*)(ws + (size_t)(8u << 20));
    unsigned short* wprojb = (unsigned short*)(ws + (size_t)(14u << 20));
    unsigned short* qkvb   = (unsigned short*)(ws + (size_t)(16u << 20));
    unsigned short* attno  = xb;

    cast_bf16_kernel<<<2048, 256, 0, stream>>>(x, xb, 524288);
    cast_bf16_kernel<<<1536, 256, 0, stream>>>(qkv_w, wqkvb, 393216);
    cast_bf16_kernel<<<512, 256, 0, stream>>>(proj_w, wprojb, 131072);

    hipFuncSetAttribute((const void*)gemm_qkv8,
                        hipFuncAttributeMaxDynamicSharedMemorySize, 98304);
    gemm_qkv8<<<dim3(12, 16), 512, 98304, stream>>>(xb, wqkvb, qkvb, 4096, 3072, 1024);
    rope_kernel<<<2048, 256, 0, stream>>>(qkvb, cosp, sinp);
    attn_kernel<<<dim3(16, 32), 256, 0, stream>>>(qkvb, attno);
    gemm_bt<1><<<dim3(8, 32), 256, 0, stream>>>(attno, wprojb, d_out, proj_b, 4096, 1024, 1024);
}

// Round 10
// 132.570 us; speedup vs baseline: 1.0198x; 1.0198x over previous
//
#include <hip/hip_runtime.h>
#include <stdint.h>

typedef __bf16 bf16;
typedef bf16 bf16x8 __attribute__((ext_vector_type(8)));
typedef float f32x4 __attribute__((ext_vector_type(4)));
typedef float f32x16 __attribute__((ext_vector_type(16)));
typedef unsigned short u16x8 __attribute__((ext_vector_type(8)));
typedef unsigned short u16x4 __attribute__((ext_vector_type(4)));

__device__ __forceinline__ unsigned short f2bfu(float f) {
    union { bf16 h; unsigned short u; } x;
    x.h = (bf16)f;
    return x.u;
}
__device__ __forceinline__ float bfu2f(unsigned short u) {
    union { unsigned int i; float f; } x;
    x.i = ((unsigned int)u) << 16;
    return x.f;
}
__device__ __forceinline__ unsigned int pack2bf(float a, float b) {
    union { bf16 h[2]; unsigned int u; } x;
    x.h[0] = (bf16)a; x.h[1] = (bf16)b;
    return x.u;
}
// v_permlane32_swap_b32: a's upper 32 lanes <-> b's lower 32 lanes.
__device__ __forceinline__ void pl32_swap(unsigned int &a, unsigned int &b) {
    asm volatile("v_permlane32_swap_b32 %0, %1" : "+v"(a), "+v"(b));
}

// global -> LDS async copy, 16B per lane. LDS dest must be wave-uniform.
__device__ __forceinline__ void gld_lds16(const void* g, void* l) {
    __builtin_amdgcn_global_load_lds(
        (const __attribute__((address_space(1))) unsigned int*)(uintptr_t)g,
        (__attribute__((address_space(3))) unsigned int*)(unsigned int)(uintptr_t)l,
        16, 0, 0);
}

// ---------------- cast fp32 -> bf16, 8 elems/thread ----------------
__global__ void cast_bf16_kernel(const float* __restrict__ in,
                                 unsigned short* __restrict__ out, int n8) {
    int i = blockIdx.x * blockDim.x + threadIdx.x;
    if (i >= n8) return;
    const f32x4* p = (const f32x4*)(in + (size_t)i * 8);
    f32x4 a = p[0], b = p[1];
    u16x8 o;
    o[0]=f2bfu(a[0]); o[1]=f2bfu(a[1]); o[2]=f2bfu(a[2]); o[3]=f2bfu(a[3]);
    o[4]=f2bfu(b[0]); o[5]=f2bfu(b[1]); o[6]=f2bfu(b[2]); o[7]=f2bfu(b[3]);
    *(u16x8*)(out + (size_t)i * 8) = o;
}

// ---------------- RoPE in-place on q,k sections of qkv [4096][3072] bf16 ----
// q additionally scaled by 0.125*log2(e) (softmax scale folded + exp->exp2).
__global__ void rope_kernel(unsigned short* __restrict__ qkv,
                            const float* __restrict__ cosp,
                            const float* __restrict__ sinp) {
    int tid = blockIdx.x * blockDim.x + threadIdx.x;   // 524288 total
    int i8  = tid & 3;
    int h   = (tid >> 2) & 15;
    int sel = (tid >> 6) & 1;
    int n   = (tid >> 7) & 2047;
    int b   = tid >> 18;
    size_t base = ((size_t)(b*2048 + n))*3072 + sel*1024 + h*64 + i8*8;
    u16x8 x1 = *(u16x8*)(qkv + base);
    u16x8 x2 = *(u16x8*)(qkv + base + 32);
    const f32x4* cp = (const f32x4*)(cosp + n*64 + i8*8);
    const f32x4* sp = (const f32x4*)(sinp + n*64 + i8*8);
    f32x4 c0 = cp[0], c1 = cp[1], s0 = sp[0], s1 = sp[1];
    float scale = sel ? 1.0f : (0.125f * 1.44269504088896f);
    u16x8 o1, o2;
#pragma unroll
    for (int j = 0; j < 8; j++) {
        float cc = (j < 4) ? c0[j] : c1[j-4];
        float ss = (j < 4) ? s0[j] : s1[j-4];
        float a = bfu2f(x1[j]), d = bfu2f(x2[j]);
        o1[j] = f2bfu((a*cc - d*ss) * scale);
        o2[j] = f2bfu((d*cc + a*ss) * scale);
    }
    *(u16x8*)(qkv + base)      = o1;
    *(u16x8*)(qkv + base + 32) = o2;
}

// ---------------- QKV GEMM, 256x256 tile, 8 waves, triple-buffer 2-ahead ----
__global__ __launch_bounds__(512, 2) void gemm_qkv8(
    const unsigned short* __restrict__ A, const unsigned short* __restrict__ B,
    unsigned short* __restrict__ C, int M, int N, int K)
{
    extern __shared__ char smem[];        // 3 bufs x (A 16KB + B 16KB) = 96KB
    int nwgx = gridDim.x;
    int nwg  = nwgx * gridDim.y;          // 192, divisible by 8
    int orig = blockIdx.y * nwgx + blockIdx.x;
    int cpx  = nwg >> 3;
    int wg   = (orig & 7) * cpx + (orig >> 3);
    int bx = wg % nwgx, by = wg / nwgx;
    int m0 = by << 8, n0 = bx << 8;
    int t  = threadIdx.x;
    int wv = t >> 6, l = t & 63;
    int fr = l & 15, fq = l >> 4;
    int wm = (wv >> 2) << 7;              // wave_m * 128
    int wn = (wv & 3) << 6;               // wave_n * 64
    int aswz = (fr & 3) << 4;

    auto stage = [&](int kt, int bsel) {
        int k0 = kt << 5;
        char* base = smem + (bsel << 15);
#pragma unroll
        for (int j = 0; j < 2; ++j) {
            int y   = (j << 13) + t * 16;             // linear LDS byte (chunk)
            int ly  = y ^ (((y >> 6) & 3) << 4);      // inverse-swizzled source
            int row = ly >> 6;
            int colu = (ly & 63) >> 1;
            gld_lds16(A + (size_t)(m0 + row) * K + k0 + colu,
                      base + ((j << 13) + (wv << 10)));
            gld_lds16(B + (size_t)(n0 + row) * K + k0 + colu,
                      base + 16384 + ((j << 13) + (wv << 10)));
        }
    };

    f32x4 acc[8][4];
#pragma unroll
    for (int m = 0; m < 8; ++m)
#pragma unroll
        for (int n = 0; n < 4; ++n) acc[m][n] = f32x4{0.f, 0.f, 0.f, 0.f};

    stage(0, 0);
    stage(1, 1);
    int cb = 0;
    for (int kt = 0; kt < 32; ++kt) {
        if (kt < 31) asm volatile("s_waitcnt vmcnt(4)" ::: "memory");
        else         asm volatile("s_waitcnt vmcnt(0)" ::: "memory");
        __builtin_amdgcn_s_barrier();
        if (kt + 2 < 32) {
            int sb = cb - 1; if (sb < 0) sb = 2;      // (cb+2)%3
            stage(kt + 2, sb);
        }
        const char* base = smem + (cb << 15);
        const char* Ab = base + ((wm + fr) << 6) + ((fq * 16) ^ aswz);
        const char* Bb = base + 16384 + ((wn + fr) << 6) + ((fq * 16) ^ aswz);
        bf16x8 bfr[4], af[4];
#pragma unroll
        for (int n = 0; n < 4; ++n) bfr[n] = *(const bf16x8*)(Bb + (n << 10));
#pragma unroll
        for (int m = 0; m < 4; ++m) af[m]  = *(const bf16x8*)(Ab + (m << 10));
        __builtin_amdgcn_s_barrier();
        __builtin_amdgcn_s_setprio(1);
#pragma unroll
        for (int m = 0; m < 4; ++m)
#pragma unroll
            for (int n = 0; n < 4; ++n)
                acc[m][n] = __builtin_amdgcn_mfma_f32_16x16x32_bf16(af[m], bfr[n], acc[m][n], 0, 0, 0);
        __builtin_amdgcn_s_setprio(0);
#pragma unroll
        for (int m = 0; m < 4; ++m) af[m] = *(const bf16x8*)(Ab + ((m + 4) << 10));
        __builtin_amdgcn_s_barrier();
        __builtin_amdgcn_s_setprio(1);
#pragma unroll
        for (int m = 0; m < 4; ++m)
#pragma unroll
            for (int n = 0; n < 4; ++n)
                acc[m + 4][n] = __builtin_amdgcn_mfma_f32_16x16x32_bf16(af[m], bfr[n], acc[m + 4][n], 0, 0, 0);
        __builtin_amdgcn_s_setprio(0);
        cb = (cb == 2) ? 0 : cb + 1;
    }
#pragma unroll
    for (int m = 0; m < 8; ++m)
#pragma unroll
        for (int n = 0; n < 4; ++n)
#pragma unroll
            for (int e = 0; e < 4; ++e) {
                int row = m0 + wm + m * 16 + fq * 4 + e;
                int col = n0 + wn + n * 16 + fr;
                C[(size_t)row * N + col] = f2bfu(acc[m][n][e]);
            }
}

// ---------------- proj GEMM: C[M,N] = A[M,K] * B[N,K]^T, f32 out + bias -----
template<int OUT_F32>
__global__ __launch_bounds__(256, 2) void gemm_bt(
    const unsigned short* __restrict__ A, const unsigned short* __restrict__ B,
    void* __restrict__ Cp, const float* __restrict__ bias,
    int M, int N, int K)
{
    __shared__ __align__(16) unsigned short As[2][128*32];
    __shared__ __align__(16) unsigned short Bs[2][128*32];
    int nwg  = gridDim.x * gridDim.y;
    int orig = blockIdx.y * gridDim.x + blockIdx.x;
    int qq = nwg >> 3, rr = nwg & 7;
    int xcd = orig & 7, idx = orig >> 3;
    int wg = (xcd < rr) ? (xcd*(qq+1) + idx) : (rr*(qq+1) + (xcd-rr)*qq + idx);
    int bx = wg % gridDim.x, by = wg / gridDim.x;
    int m0 = by * 128, n0 = bx * 128;
    int t = threadIdx.x;
    int w = t >> 6, l = t & 63;
    int c = l & 15, g = l >> 4;
    int wm = (w >> 1) * 64, wn = (w & 1) * 64;

    auto stage = [&](int kt, int bsel) {
#pragma unroll
        for (int r2 = 0; r2 < 2; ++r2) {
            int xb = w*2048 + r2*1024;        // byte base of wave chunk
            int x  = xb + l*16;               // per-lane byte
            int row  = x >> 6;                // 64B per row (32 bf16)
            int colu = (x & 63) >> 1;         // ushort col
            int k0 = kt << 5;
            gld_lds16(A + (size_t)(m0+row)*K + k0 + colu, (void*)(As[bsel] + (xb >> 1)));
            gld_lds16(B + (size_t)(n0+row)*K + k0 + colu, (void*)(Bs[bsel] + (xb >> 1)));
        }
    };

    f32x4 acc[4][4];
#pragma unroll
    for (int i = 0; i < 4; i++)
#pragma unroll
        for (int j = 0; j < 4; j++) acc[i][j] = f32x4{0.f,0.f,0.f,0.f};

    int nkt = K >> 5;
    stage(0, 0);
    int cur = 0;
    for (int kt = 0; kt < nkt; ++kt) {
        __syncthreads();                      // drains stage(kt); frees buf cur^1
        if (kt + 1 < nkt) stage(kt + 1, cur ^ 1);   // in flight through compute
        const unsigned short* Ab = As[cur] + wm*32;
        const unsigned short* Bb = Bs[cur] + wn*32;
        bf16x8 af[4], bfr[4];
#pragma unroll
        for (int i = 0; i < 4; i++) af[i]  = *(const bf16x8*)(Ab + (i*16+c)*32 + g*8);
#pragma unroll
        for (int i = 0; i < 4; i++) bfr[i] = *(const bf16x8*)(Bb + (i*16+c)*32 + g*8);
#pragma unroll
        for (int i = 0; i < 4; i++)
#pragma unroll
            for (int j = 0; j < 4; j++)
                acc[i][j] = __builtin_amdgcn_mfma_f32_16x16x32_bf16(af[i], bfr[j], acc[i][j], 0, 0, 0);
        cur ^= 1;
    }
#pragma unroll
    for (int i = 0; i < 4; i++)
#pragma unroll
        for (int j = 0; j < 4; j++)
#pragma unroll
            for (int e = 0; e < 4; e++) {
                int row = m0 + wm + i*16 + g*4 + e;
                int col = n0 + wn + j*16 + c;
                float v = acc[i][j][e];
                if (bias) v += bias[col];
                if (OUT_F32) ((float*)Cp)[(size_t)row*N + col] = v;
                else ((unsigned short*)Cp)[(size_t)row*N + col] = f2bfu(v);
            }
}

// ---------------- flash attention, 8 waves, KV-split-in-block ---------------
// grid (16 q-tiles, 32 bh). block 512 = 8 waves = 2 pairs of 4.
// Pair p handles kv-tiles [p*16, p*16+16) over the SAME 128 q-rows; each pair
// has its own double-buffered K/V LDS (64KB total -> 2 blocks/CU = 16 waves/CU,
// 2x the old occupancy). No-max softmax => partials combine by simple add:
// pair1 writes (Sigma, l) to LDS at the end; pair0 adds, divides, stores.
__global__ __launch_bounds__(512, 4) void attn_kernel(
    const unsigned short* __restrict__ qkv, unsigned short* __restrict__ outp)
{
    __shared__ __align__(16) char lds[65536];
    // K tile (pair,buf) at lds + ((pair*2+buf)*8KB); V^T at +32KB same layout.
    int bh = blockIdx.y;
    int b = bh >> 4, h = bh & 15;
    int q0 = blockIdx.x << 7;
    int t = threadIdx.x;
    int w = t >> 6, l = t & 63;
    int pair = w >> 2, wp = w & 3;
    int tp = t & 255;                       // thread index within pair
    int q = l & 31, hi = l >> 5;
    int qw = q0 + wp*32;
    size_t bh_base = ((size_t)b*2048)*3072 + (size_t)h*64;

    auto kbase = [&](int bsel) -> char* { return lds + (((pair << 1) | bsel) << 13); };
    auto vbase = [&](int bsel) -> char* { return lds + 32768 + (((pair << 1) | bsel) << 13); };

    auto stageK = [&](int kv0, int bsel) {
#pragma unroll
        for (int r2 = 0; r2 < 2; ++r2) {
            int xb = wp*2048 + r2*1024;
            int x  = xb + l*16;
            int row  = x >> 7;                 // 128B rows
            int scolb = (x & 127) ^ ((row & 7) << 4);
            gld_lds16(qkv + bh_base + 1024 + (size_t)(kv0 + row)*3072 + (scolb >> 1),
                      kbase(bsel) + xb);
        }
    };
    auto loadV = [&](int kv0, u16x8 &v0, u16x8 &v1) {
        int p  = tp >> 3;
        int hb = (tp & 7) << 3;
        const unsigned short* src = qkv + bh_base + 2048 + (size_t)(kv0 + 2*p)*3072 + hb;
        v0 = *(const u16x8*)src;
        v1 = *(const u16x8*)(src + 3072);
    };
    auto writeV = [&](const u16x8 &v0, const u16x8 &v1, int bsel) {
        int p  = tp >> 3;
        int hb = (tp & 7) << 3;
        char* vb = vbase(bsel);
#pragma unroll
        for (int e = 0; e < 8; e++) {
            int hd = hb + e;
            int colb = (4*p) ^ ((((hd) ^ (hd >> 3)) & 7) << 4);
            *(unsigned int*)(vb + hd*128 + colb) =
                (unsigned int)v0[e] | ((unsigned int)v1[e] << 16);
        }
    };

    // Q B-frags: qf[dc] = Q[qw+q][dc*16 + hi*8 .. +7]  (duplicated per pair)
    bf16x8 qf[4];
#pragma unroll
    for (int dc = 0; dc < 4; dc++)
        qf[dc] = *(const bf16x8*)(qkv + bh_base + (size_t)(qw + q)*3072 + dc*16 + hi*8);

    f32x16 oacc[2];
#pragma unroll
    for (int e = 0; e < 16; e++) { oacc[0][e] = 0.f; oacc[1][e] = 0.f; }
    float lsum = 0.f;

    int tile0 = pair << 4;                    // 16 kv-tiles per pair
    u16x8 vc0, vc1, vn0, vn1;
    stageK(tile0 << 6, 0);
    loadV(tile0 << 6, vc0, vc1);
    int cur = 0;

    for (int it = 0; it < 16; ++it) {
        writeV(vc0, vc1, cur);                 // waits V regs (counted vmcnt)
        __syncthreads();                       // K(t) landed; compute(t-1) done
        if (it < 15) {
            int kv0n = (tile0 + it + 1) << 6;
            stageK(kv0n, cur ^ 1);             // in flight through compute(t)
            loadV(kv0n, vn0, vn1);
        }
        const char* ksb = kbase(cur);
        const char* vtb = vbase(cur);

#pragma unroll
        for (int sblk = 0; sblk < 2; ++sblk) {
            // S^T block [32 kv][32 q] = K * Q^T : 4 MFMA over d
            f32x16 st;
#pragma unroll
            for (int e = 0; e < 16; e++) st[e] = 0.f;
            int krow = sblk*32 + q;
            int ksw = (krow & 7) << 4;
#pragma unroll
            for (int dc = 0; dc < 4; ++dc) {
                bf16x8 kf = *(const bf16x8*)(ksb + krow*128 + ((dc*32 + hi*16) ^ ksw));
                st = __builtin_amdgcn_mfma_f32_32x32x16_bf16(kf, qf[dc], st, 0, 0, 0);
            }
            // softmax: P = exp2(S') (log2e pre-folded); pack pairs; row-sum
            unsigned int wds[8];
#pragma unroll
            for (int m = 0; m < 8; m++) {
                float p0 = __builtin_amdgcn_exp2f(st[2*m]);
                float p1 = __builtin_amdgcn_exp2f(st[2*m+1]);
                lsum += p0 + p1;
                wds[m] = pack2bf(p0, p1);
            }
            // PV: per 16-kv chunk assemble P^T B-frag via 2 swaps, 2 MFMA
#pragma unroll
            for (int half = 0; half < 2; ++half) {
                unsigned int a0 = wds[half*4 + 0], b0 = wds[half*4 + 2];
                unsigned int a1 = wds[half*4 + 1], b1 = wds[half*4 + 3];
                pl32_swap(a0, b0);
                pl32_swap(a1, b1);
                union { unsigned int u[4]; bf16x8 v; } pf;
                pf.u[0] = a0; pf.u[1] = a1; pf.u[2] = b0; pf.u[3] = b1;
                int kc = sblk*2 + half;
#pragma unroll
                for (int hdblk = 0; hdblk < 2; ++hdblk) {
                    int hd = hdblk*32 + q;
                    int vsw = ((hd ^ (hd >> 3)) & 7) << 4;
                    bf16x8 vf = *(const bf16x8*)(vtb + hd*128 + ((kc*32 + hi*16) ^ vsw));
                    oacc[hdblk] = __builtin_amdgcn_mfma_f32_32x32x16_bf16(vf, pf.v, oacc[hdblk], 0, 0, 0);
                }
            }
        }
        vc0 = vn0; vc1 = vn1;
        cur ^= 1;
    }
    // pair-local column sum (lanes q / q+32 hold same column)
    float lt = lsum + __shfl_xor(lsum, 32, 64);

    // cross-pair combine via LDS: pair1 writes Sigma (32 f32/lane) + l; pair0
    // adds, normalizes, stores. XOR chunk swizzle keeps ds ops conflict-free.
    __syncthreads();                           // all compute done; LDS free
    int cbase = ((wp << 6) + l) << 7;          // 128B per lane, 32KB total
    int swl = (l & 7) << 4;
    if (pair == 1) {
#pragma unroll
        for (int j = 0; j < 8; ++j) {
            int hb = j >> 2, qd = j & 3;
            f32x4 v = f32x4{oacc[hb][qd*4+0], oacc[hb][qd*4+1],
                            oacc[hb][qd*4+2], oacc[hb][qd*4+3]};
            *(f32x4*)(lds + cbase + ((j << 4) ^ swl)) = v;
        }
        ((float*)(lds + 32768))[(wp << 6) + l] = lt;
    }
    __syncthreads();
    if (pair == 0) {
#pragma unroll
        for (int j = 0; j < 8; ++j) {
            int hb = j >> 2, qd = j & 3;
            f32x4 v = *(const f32x4*)(lds + cbase + ((j << 4) ^ swl));
#pragma unroll
            for (int e = 0; e < 4; ++e) oacc[hb][qd*4+e] += v[e];
        }
        lt += ((float*)(lds + 32768))[(wp << 6) + l];
        float rinv = 1.0f / lt;
        size_t orow = (size_t)(b*2048 + qw + q) * 1024 + h*64;
#pragma unroll
        for (int hdblk = 0; hdblk < 2; ++hdblk)
#pragma unroll
            for (int quad = 0; quad < 4; ++quad) {
                u16x4 o4;
#pragma unroll
                for (int j = 0; j < 4; j++)
                    o4[j] = f2bfu(oacc[hdblk][quad*4 + j] * rinv);
                *(u16x4*)(outp + orow + hdblk*32 + quad*8 + hi*4) = o4;
            }
    }
}

// ---------------- launch ----------------------------------------------------
extern "C" void kernel_launch(void* const* d_in, const int* in_sizes, int n_in,
                              void* d_out, int out_size, void* d_ws, size_t ws_size,
                              hipStream_t stream) {
    const float* x      = (const float*)d_in[0];
    const float* cosp   = (const float*)d_in[1];
    const float* sinp   = (const float*)d_in[2];
    const float* qkv_w  = (const float*)d_in[3];
    const float* proj_w = (const float*)d_in[4];
    const float* proj_b = (const float*)d_in[5];

    char* ws = (char*)d_ws;
    unsigned short* xb     = (unsigned short*)(ws);
    unsigned short* wqkvb  = (unsigned short*)(ws + (size_t)(8u << 20));
    unsigned short* wprojb = (unsigned short*)(ws + (size_t)(14u << 20));
    unsigned short* qkvb   = (unsigned short*)(ws + (size_t)(16u << 20));
    unsigned short* attno  = xb;

    cast_bf16_kernel<<<2048, 256, 0, stream>>>(x, xb, 524288);
    cast_bf16_kernel<<<1536, 256, 0, stream>>>(qkv_w, wqkvb, 393216);
    cast_bf16_kernel<<<512, 256, 0, stream>>>(proj_w, wprojb, 131072);

    hipFuncSetAttribute((const void*)gemm_qkv8,
                        hipFuncAttributeMaxDynamicSharedMemorySize, 98304);
    gemm_qkv8<<<dim3(12, 16), 512, 98304, stream>>>(xb, wqkvb, qkvb, 4096, 3072, 1024);
    rope_kernel<<<2048, 256, 0, stream>>>(qkvb, cosp, sinp);
    attn_kernel<<<dim3(16, 32), 512, 0, stream>>>(qkvb, attno);
    gemm_bt<1><<<dim3(8, 32), 256, 0, stream>>>(attno, wprojb, d_out, proj_b, 4096, 1024, 1024);
}

// Round 11
// 123.391 us; speedup vs baseline: 1.0956x; 1.0744x over previous
//
#include <hip/hip_runtime.h>
#include <stdint.h>

typedef __bf16 bf16;
typedef bf16 bf16x8 __attribute__((ext_vector_type(8)));
typedef float f32x4 __attribute__((ext_vector_type(4)));
typedef float f32x16 __attribute__((ext_vector_type(16)));
typedef unsigned short u16x8 __attribute__((ext_vector_type(8)));
typedef unsigned short u16x4 __attribute__((ext_vector_type(4)));

__device__ __forceinline__ unsigned short f2bfu(float f) {
    union { bf16 h; unsigned short u; } x;
    x.h = (bf16)f;
    return x.u;
}
__device__ __forceinline__ float bfu2f(unsigned short u) {
    union { unsigned int i; float f; } x;
    x.i = ((unsigned int)u) << 16;
    return x.f;
}
__device__ __forceinline__ unsigned int pack2bf(float a, float b) {
    union { bf16 h[2]; unsigned int u; } x;
    x.h[0] = (bf16)a; x.h[1] = (bf16)b;
    return x.u;
}
// v_permlane32_swap_b32: a's upper 32 lanes <-> b's lower 32 lanes.
__device__ __forceinline__ void pl32_swap(unsigned int &a, unsigned int &b) {
    asm volatile("v_permlane32_swap_b32 %0, %1" : "+v"(a), "+v"(b));
}

// global -> LDS async copy, 16B per lane. LDS dest must be wave-uniform.
__device__ __forceinline__ void gld_lds16(const void* g, void* l) {
    __builtin_amdgcn_global_load_lds(
        (const __attribute__((address_space(1))) unsigned int*)(uintptr_t)g,
        (__attribute__((address_space(3))) unsigned int*)(unsigned int)(uintptr_t)l,
        16, 0, 0);
}

// ---------------- fused cast fp32 -> bf16 for x, qkv_w, proj_w --------------
// 8-elem units: x 524288 | qkv_w 393216 | proj_w 131072 (sum = 1048576)
__global__ void cast3_kernel(const float* __restrict__ x,
                             const float* __restrict__ w1,
                             const float* __restrict__ w2,
                             unsigned short* __restrict__ ox,
                             unsigned short* __restrict__ o1,
                             unsigned short* __restrict__ o2) {
    int i = blockIdx.x * blockDim.x + threadIdx.x;
    const float* in; unsigned short* out; int k;
    if (i < 524288)       { in = x;  out = ox; k = i; }
    else if (i < 917504)  { in = w1; out = o1; k = i - 524288; }
    else                  { in = w2; out = o2; k = i - 917504; }
    const f32x4* p = (const f32x4*)(in + (size_t)k * 8);
    f32x4 a = p[0], b = p[1];
    u16x8 o;
    o[0]=f2bfu(a[0]); o[1]=f2bfu(a[1]); o[2]=f2bfu(a[2]); o[3]=f2bfu(a[3]);
    o[4]=f2bfu(b[0]); o[5]=f2bfu(b[1]); o[6]=f2bfu(b[2]); o[7]=f2bfu(b[3]);
    *(u16x8*)(out + (size_t)k * 8) = o;
}

// ---------------- RoPE in-place on q,k sections of qkv [4096][3072] bf16 ----
// q additionally scaled by 0.125*log2(e) (softmax scale folded + exp->exp2).
__global__ void rope_kernel(unsigned short* __restrict__ qkv,
                            const float* __restrict__ cosp,
                            const float* __restrict__ sinp) {
    int tid = blockIdx.x * blockDim.x + threadIdx.x;   // 524288 total
    int i8  = tid & 3;
    int h   = (tid >> 2) & 15;
    int sel = (tid >> 6) & 1;
    int n   = (tid >> 7) & 2047;
    int b   = tid >> 18;
    size_t base = ((size_t)(b*2048 + n))*3072 + sel*1024 + h*64 + i8*8;
    u16x8 x1 = *(u16x8*)(qkv + base);
    u16x8 x2 = *(u16x8*)(qkv + base + 32);
    const f32x4* cp = (const f32x4*)(cosp + n*64 + i8*8);
    const f32x4* sp = (const f32x4*)(sinp + n*64 + i8*8);
    f32x4 c0 = cp[0], c1 = cp[1], s0 = sp[0], s1 = sp[1];
    float scale = sel ? 1.0f : (0.125f * 1.44269504088896f);
    u16x8 o1, o2;
#pragma unroll
    for (int j = 0; j < 8; j++) {
        float cc = (j < 4) ? c0[j] : c1[j-4];
        float ss = (j < 4) ? s0[j] : s1[j-4];
        float a = bfu2f(x1[j]), d = bfu2f(x2[j]);
        o1[j] = f2bfu((a*cc - d*ss) * scale);
        o2[j] = f2bfu((d*cc + a*ss) * scale);
    }
    *(u16x8*)(qkv + base)      = o1;
    *(u16x8*)(qkv + base + 32) = o2;
}

// ---------------- QKV GEMM, 256x128 tile, 8 waves, triple-buffer 2-ahead ----
// grid 24x16 = 384 blocks (%8==0, all co-resident: 72KB LDS -> 2 blocks/CU).
// Single s_barrier per K-step, counted vmcnt(3) (never 0 mid-loop), 2-way
// read swizzle slot ^= (row>>1)&3 (write-side via inverse-swizzled source).
__global__ __launch_bounds__(512, 2) void gemm_qkv8b(
    const unsigned short* __restrict__ A, const unsigned short* __restrict__ B,
    unsigned short* __restrict__ C, int M, int N, int K)
{
    extern __shared__ char smem[];        // 3 bufs x (A 16KB + B 8KB) = 72KB
    int nwgx = gridDim.x;
    int nwg  = nwgx * gridDim.y;          // 384
    int orig = blockIdx.y * nwgx + blockIdx.x;
    int cpx  = nwg >> 3;
    int wg   = (orig & 7) * cpx + (orig >> 3);
    int bx = wg % nwgx, by = wg / nwgx;
    int m0 = by << 8, n0 = bx << 7;
    int t  = threadIdx.x;
    int wv = t >> 6, l = t & 63;
    int fr = l & 15, fq = l >> 4;
    int wm = (wv >> 1) << 6;              // 4 M-waves * 64
    int wn = (wv & 1) << 6;               // 2 N-waves * 64

    auto stage = [&](int kt, int bsel) {
        int k0 = kt << 5;
        char* base = smem + bsel * 24576;
#pragma unroll
        for (int j = 0; j < 2; ++j) {     // A: 16KB, 2 loads/thread
            int y  = (j << 13) + t * 16;
            int ly = y ^ (((y >> 7) & 3) << 4);
            int row = ly >> 6, colu = (ly & 63) >> 1;
            gld_lds16(A + (size_t)(m0 + row) * K + k0 + colu,
                      base + (j << 13) + (wv << 10));
        }
        {                                  // B: 8KB, 1 load/thread
            int y  = t * 16;
            int ly = y ^ (((y >> 7) & 3) << 4);
            int row = ly >> 6, colu = (ly & 63) >> 1;
            gld_lds16(B + (size_t)(n0 + row) * K + k0 + colu,
                      base + 16384 + (wv << 10));
        }
    };

    f32x4 acc[4][4];
#pragma unroll
    for (int i = 0; i < 4; i++)
#pragma unroll
        for (int j = 0; j < 4; j++) acc[i][j] = f32x4{0.f,0.f,0.f,0.f};

    stage(0, 0);
    stage(1, 1);
    int cb = 0;
    for (int kt = 0; kt < 32; ++kt) {
        if (kt < 31) asm volatile("s_waitcnt vmcnt(3)" ::: "memory");
        else         asm volatile("s_waitcnt vmcnt(0)" ::: "memory");
        __builtin_amdgcn_s_barrier();     // tile kt ready; tile kt-1 consumed
        if (kt + 2 < 32) {
            int sb = cb - 1; if (sb < 0) sb = 2;      // (cb+2)%3
            stage(kt + 2, sb);
        }
        const char* base = smem + cb * 24576;
        bf16x8 af[4], bfr[4];
#pragma unroll
        for (int m = 0; m < 4; ++m) {
            int row = wm + m*16 + fr;
            af[m] = *(const bf16x8*)(base + row*64 + ((fq ^ ((row >> 1) & 3)) << 4));
        }
#pragma unroll
        for (int n = 0; n < 4; ++n) {
            int row = wn + n*16 + fr;
            bfr[n] = *(const bf16x8*)(base + 16384 + row*64 + ((fq ^ ((row >> 1) & 3)) << 4));
        }
        __builtin_amdgcn_s_setprio(1);
#pragma unroll
        for (int m = 0; m < 4; ++m)
#pragma unroll
            for (int n = 0; n < 4; ++n)
                acc[m][n] = __builtin_amdgcn_mfma_f32_16x16x32_bf16(af[m], bfr[n], acc[m][n], 0, 0, 0);
        __builtin_amdgcn_s_setprio(0);
        cb = (cb == 2) ? 0 : cb + 1;
    }
#pragma unroll
    for (int m = 0; m < 4; ++m)
#pragma unroll
        for (int n = 0; n < 4; ++n)
#pragma unroll
            for (int e = 0; e < 4; ++e) {
                int row = m0 + wm + m*16 + fq*4 + e;
                int col = n0 + wn + n*16 + fr;
                C[(size_t)row * N + col] = f2bfu(acc[m][n][e]);
            }
}

// ---------------- proj GEMM: C[M,N] = A[M,K] * B[N,K]^T, f32 out + bias -----
// dbuf + single barrier per K-step; 2-way read swizzle added this round.
template<int OUT_F32>
__global__ __launch_bounds__(256, 2) void gemm_bt(
    const unsigned short* __restrict__ A, const unsigned short* __restrict__ B,
    void* __restrict__ Cp, const float* __restrict__ bias,
    int M, int N, int K)
{
    __shared__ __align__(16) unsigned short As[2][128*32];
    __shared__ __align__(16) unsigned short Bs[2][128*32];
    int nwg  = gridDim.x * gridDim.y;
    int orig = blockIdx.y * gridDim.x + blockIdx.x;
    int qq = nwg >> 3, rr = nwg & 7;
    int xcd = orig & 7, idx = orig >> 3;
    int wg = (xcd < rr) ? (xcd*(qq+1) + idx) : (rr*(qq+1) + (xcd-rr)*qq + idx);
    int bx = wg % gridDim.x, by = wg / gridDim.x;
    int m0 = by * 128, n0 = bx * 128;
    int t = threadIdx.x;
    int w = t >> 6, l = t & 63;
    int c = l & 15, g = l >> 4;
    int wm = (w >> 1) * 64, wn = (w & 1) * 64;

    auto stage = [&](int kt, int bsel) {
#pragma unroll
        for (int r2 = 0; r2 < 2; ++r2) {
            int xb = w*2048 + r2*1024;        // byte base of wave chunk
            int x  = xb + l*16;               // per-lane byte
            int lx = x ^ (((x >> 7) & 3) << 4);
            int row  = lx >> 6;               // 64B per row (32 bf16)
            int colu = (lx & 63) >> 1;        // ushort col
            int k0 = kt << 5;
            gld_lds16(A + (size_t)(m0+row)*K + k0 + colu, (void*)(As[bsel] + (xb >> 1)));
            gld_lds16(B + (size_t)(n0+row)*K + k0 + colu, (void*)(Bs[bsel] + (xb >> 1)));
        }
    };

    f32x4 acc[4][4];
#pragma unroll
    for (int i = 0; i < 4; i++)
#pragma unroll
        for (int j = 0; j < 4; j++) acc[i][j] = f32x4{0.f,0.f,0.f,0.f};

    int nkt = K >> 5;
    stage(0, 0);
    int cur = 0;
    for (int kt = 0; kt < nkt; ++kt) {
        __syncthreads();                      // drains stage(kt); frees buf cur^1
        if (kt + 1 < nkt) stage(kt + 1, cur ^ 1);   // in flight through compute
        const char* Ab = (const char*)As[cur];
        const char* Bb = (const char*)Bs[cur];
        bf16x8 af[4], bfr[4];
#pragma unroll
        for (int i = 0; i < 4; i++) {
            int rowa = wm + i*16 + c;
            int rowb = wn + i*16 + c;
            af[i]  = *(const bf16x8*)(Ab + rowa*64 + ((g ^ ((rowa >> 1) & 3)) << 4));
            bfr[i] = *(const bf16x8*)(Bb + rowb*64 + ((g ^ ((rowb >> 1) & 3)) << 4));
        }
        __builtin_amdgcn_s_setprio(1);
#pragma unroll
        for (int i = 0; i < 4; i++)
#pragma unroll
            for (int j = 0; j < 4; j++)
                acc[i][j] = __builtin_amdgcn_mfma_f32_16x16x32_bf16(af[i], bfr[j], acc[i][j], 0, 0, 0);
        __builtin_amdgcn_s_setprio(0);
        cur ^= 1;
    }
#pragma unroll
    for (int i = 0; i < 4; i++)
#pragma unroll
        for (int j = 0; j < 4; j++)
#pragma unroll
            for (int e = 0; e < 4; e++) {
                int row = m0 + wm + i*16 + g*4 + e;
                int col = n0 + wn + j*16 + c;
                float v = acc[i][j][e];
                if (bias) v += bias[col];
                if (OUT_F32) ((float*)Cp)[(size_t)row*N + col] = v;
                else ((unsigned short*)Cp)[(size_t)row*N + col] = f2bfu(v);
            }
}

// ---------------- flash attention, 8 waves, KV-split-in-block ---------------
// grid (16 q-tiles, 32 bh). block 512 = 8 waves = 2 pairs of 4.
// Pair p handles kv-tiles [p*16, p*16+16) over the SAME 128 q-rows; each pair
// has its own double-buffered K/V LDS (64KB total -> 2 blocks/CU = 16 waves/CU).
// No-max softmax => partials combine by simple add at the end.
// This round: + s_setprio(1) around MFMA clusters (T5).
__global__ __launch_bounds__(512, 4) void attn_kernel(
    const unsigned short* __restrict__ qkv, unsigned short* __restrict__ outp)
{
    __shared__ __align__(16) char lds[65536];
    int bh = blockIdx.y;
    int b = bh >> 4, h = bh & 15;
    int q0 = blockIdx.x << 7;
    int t = threadIdx.x;
    int w = t >> 6, l = t & 63;
    int pair = w >> 2, wp = w & 3;
    int tp = t & 255;                       // thread index within pair
    int q = l & 31, hi = l >> 5;
    int qw = q0 + wp*32;
    size_t bh_base = ((size_t)b*2048)*3072 + (size_t)h*64;

    auto kbase = [&](int bsel) -> char* { return lds + (((pair << 1) | bsel) << 13); };
    auto vbase = [&](int bsel) -> char* { return lds + 32768 + (((pair << 1) | bsel) << 13); };

    auto stageK = [&](int kv0, int bsel) {
#pragma unroll
        for (int r2 = 0; r2 < 2; ++r2) {
            int xb = wp*2048 + r2*1024;
            int x  = xb + l*16;
            int row  = x >> 7;                 // 128B rows
            int scolb = (x & 127) ^ ((row & 7) << 4);
            gld_lds16(qkv + bh_base + 1024 + (size_t)(kv0 + row)*3072 + (scolb >> 1),
                      kbase(bsel) + xb);
        }
    };
    auto loadV = [&](int kv0, u16x8 &v0, u16x8 &v1) {
        int p  = tp >> 3;
        int hb = (tp & 7) << 3;
        const unsigned short* src = qkv + bh_base + 2048 + (size_t)(kv0 + 2*p)*3072 + hb;
        v0 = *(const u16x8*)src;
        v1 = *(const u16x8*)(src + 3072);
    };
    auto writeV = [&](const u16x8 &v0, const u16x8 &v1, int bsel) {
        int p  = tp >> 3;
        int hb = (tp & 7) << 3;
        char* vb = vbase(bsel);
#pragma unroll
        for (int e = 0; e < 8; e++) {
            int hd = hb + e;
            int colb = (4*p) ^ ((((hd) ^ (hd >> 3)) & 7) << 4);
            *(unsigned int*)(vb + hd*128 + colb) =
                (unsigned int)v0[e] | ((unsigned int)v1[e] << 16);
        }
    };

    // Q B-frags: qf[dc] = Q[qw+q][dc*16 + hi*8 .. +7]  (duplicated per pair)
    bf16x8 qf[4];
#pragma unroll
    for (int dc = 0; dc < 4; dc++)
        qf[dc] = *(const bf16x8*)(qkv + bh_base + (size_t)(qw + q)*3072 + dc*16 + hi*8);

    f32x16 oacc[2];
#pragma unroll
    for (int e = 0; e < 16; e++) { oacc[0][e] = 0.f; oacc[1][e] = 0.f; }
    float lsum = 0.f;

    int tile0 = pair << 4;                    // 16 kv-tiles per pair
    u16x8 vc0, vc1, vn0, vn1;
    stageK(tile0 << 6, 0);
    loadV(tile0 << 6, vc0, vc1);
    int cur = 0;

    for (int it = 0; it < 16; ++it) {
        writeV(vc0, vc1, cur);                 // waits V regs (counted vmcnt)
        __syncthreads();                       // K(t) landed; compute(t-1) done
        if (it < 15) {
            int kv0n = (tile0 + it + 1) << 6;
            stageK(kv0n, cur ^ 1);             // in flight through compute(t)
            loadV(kv0n, vn0, vn1);
        }
        const char* ksb = kbase(cur);
        const char* vtb = vbase(cur);

#pragma unroll
        for (int sblk = 0; sblk < 2; ++sblk) {
            // S^T block [32 kv][32 q] = K * Q^T : 4 MFMA over d
            f32x16 st;
#pragma unroll
            for (int e = 0; e < 16; e++) st[e] = 0.f;
            int krow = sblk*32 + q;
            int ksw = (krow & 7) << 4;
            __builtin_amdgcn_s_setprio(1);
#pragma unroll
            for (int dc = 0; dc < 4; ++dc) {
                bf16x8 kf = *(const bf16x8*)(ksb + krow*128 + ((dc*32 + hi*16) ^ ksw));
                st = __builtin_amdgcn_mfma_f32_32x32x16_bf16(kf, qf[dc], st, 0, 0, 0);
            }
            __builtin_amdgcn_s_setprio(0);
            // softmax: P = exp2(S') (log2e pre-folded); pack pairs; row-sum
            unsigned int wds[8];
#pragma unroll
            for (int m = 0; m < 8; m++) {
                float p0 = __builtin_amdgcn_exp2f(st[2*m]);
                float p1 = __builtin_amdgcn_exp2f(st[2*m+1]);
                lsum += p0 + p1;
                wds[m] = pack2bf(p0, p1);
            }
            // PV: per 16-kv chunk assemble P^T B-frag via 2 swaps, 2 MFMA
#pragma unroll
            for (int half = 0; half < 2; ++half) {
                unsigned int a0 = wds[half*4 + 0], b0 = wds[half*4 + 2];
                unsigned int a1 = wds[half*4 + 1], b1 = wds[half*4 + 3];
                pl32_swap(a0, b0);
                pl32_swap(a1, b1);
                union { unsigned int u[4]; bf16x8 v; } pf;
                pf.u[0] = a0; pf.u[1] = a1; pf.u[2] = b0; pf.u[3] = b1;
                int kc = sblk*2 + half;
                __builtin_amdgcn_s_setprio(1);
#pragma unroll
                for (int hdblk = 0; hdblk < 2; ++hdblk) {
                    int hd = hdblk*32 + q;
                    int vsw = ((hd ^ (hd >> 3)) & 7) << 4;
                    bf16x8 vf = *(const bf16x8*)(vtb + hd*128 + ((kc*32 + hi*16) ^ vsw));
                    oacc[hdblk] = __builtin_amdgcn_mfma_f32_32x32x16_bf16(vf, pf.v, oacc[hdblk], 0, 0, 0);
                }
                __builtin_amdgcn_s_setprio(0);
            }
        }
        vc0 = vn0; vc1 = vn1;
        cur ^= 1;
    }
    // pair-local column sum (lanes q / q+32 hold same column)
    float lt = lsum + __shfl_xor(lsum, 32, 64);

    // cross-pair combine via LDS: pair1 writes Sigma (32 f32/lane) + l; pair0
    // adds, normalizes, stores. XOR chunk swizzle keeps ds ops conflict-free.
    __syncthreads();                           // all compute done; LDS free
    int cbase = ((wp << 6) + l) << 7;          // 128B per lane, 32KB total
    int swl = (l & 7) << 4;
    if (pair == 1) {
#pragma unroll
        for (int j = 0; j < 8; ++j) {
            int hb = j >> 2, qd = j & 3;
            f32x4 v = f32x4{oacc[hb][qd*4+0], oacc[hb][qd*4+1],
                            oacc[hb][qd*4+2], oacc[hb][qd*4+3]};
            *(f32x4*)(lds + cbase + ((j << 4) ^ swl)) = v;
        }
        ((float*)(lds + 32768))[(wp << 6) + l] = lt;
    }
    __syncthreads();
    if (pair == 0) {
#pragma unroll
        for (int j = 0; j < 8; ++j) {
            int hb = j >> 2, qd = j & 3;
            f32x4 v = *(const f32x4*)(lds + cbase + ((j << 4) ^ swl));
#pragma unroll
            for (int e = 0; e < 4; ++e) oacc[hb][qd*4+e] += v[e];
        }
        lt += ((float*)(lds + 32768))[(wp << 6) + l];
        float rinv = 1.0f / lt;
        size_t orow = (size_t)(b*2048 + qw + q) * 1024 + h*64;
#pragma unroll
        for (int hdblk = 0; hdblk < 2; ++hdblk)
#pragma unroll
            for (int quad = 0; quad < 4; ++quad) {
                u16x4 o4;
#pragma unroll
                for (int j = 0; j < 4; j++)
                    o4[j] = f2bfu(oacc[hdblk][quad*4 + j] * rinv);
                *(u16x4*)(outp + orow + hdblk*32 + quad*8 + hi*4) = o4;
            }
    }
}

// ---------------- launch ----------------------------------------------------
extern "C" void kernel_launch(void* const* d_in, const int* in_sizes, int n_in,
                              void* d_out, int out_size, void* d_ws, size_t ws_size,
                              hipStream_t stream) {
    const float* x      = (const float*)d_in[0];
    const float* cosp   = (const float*)d_in[1];
    const float* sinp   = (const float*)d_in[2];
    const float* qkv_w  = (const float*)d_in[3];
    const float* proj_w = (const float*)d_in[4];
    const float* proj_b = (const float*)d_in[5];

    char* ws = (char*)d_ws;
    unsigned short* xb     = (unsigned short*)(ws);
    unsigned short* wqkvb  = (unsigned short*)(ws + (size_t)(8u << 20));
    unsigned short* wprojb = (unsigned short*)(ws + (size_t)(14u << 20));
    unsigned short* qkvb   = (unsigned short*)(ws + (size_t)(16u << 20));
    unsigned short* attno  = xb;

    cast3_kernel<<<4096, 256, 0, stream>>>(x, qkv_w, proj_w, xb, wqkvb, wprojb);

    hipFuncSetAttribute((const void*)gemm_qkv8b,
                        hipFuncAttributeMaxDynamicSharedMemorySize, 73728);
    gemm_qkv8b<<<dim3(24, 16), 512, 73728, stream>>>(xb, wqkvb, qkvb, 4096, 3072, 1024);
    rope_kernel<<<2048, 256, 0, stream>>>(qkvb, cosp, sinp);
    attn_kernel<<<dim3(16, 32), 512, 0, stream>>>(qkvb, attno);
    gemm_bt<1><<<dim3(8, 32), 256, 0, stream>>>(attno, wprojb, d_out, proj_b, 4096, 1024, 1024);
}